// Round 3
// baseline (309.264 us; speedup 1.0000x reference)
//
#include <hip/hip_runtime.h>

#define DCH 512     // channels

__global__ __launch_bounds__(128) void ppeg_dwconv_kernel(
    const float* __restrict__ x,
    const float* __restrict__ w3, const float* __restrict__ b3,
    const float* __restrict__ w5, const float* __restrict__ b5,
    const float* __restrict__ w7, const float* __restrict__ b7,
    const int* __restrict__ lengths,
    float* __restrict__ out, int n_rows, int n_bags)
{
    __shared__ int soff[32];   // prefix offsets, n_bags+1 entries
    if (threadIdx.x == 0) {
        int acc = 0;
        for (int i = 0; i < n_bags; ++i) { soff[i] = acc; acc += lengths[i]; }
        soff[n_bags] = acc;
    }
    __syncthreads();

    const int tid = threadIdx.x;
    const int c0  = tid * 4;           // this thread's 4 channels

    const int r0 = blockIdx.x * 2;     // this block: rows r0, r0+1
    if (r0 >= n_rows) return;
    const int r1 = r0 + 1;

    // 8 independent loads covering rows r0-3 .. r0+4 (window for both rows).
    // Out-of-range rows clamp to a valid address; their taps are always masked.
    float4 v[8];
    #pragma unroll
    for (int j = 0; j < 8; ++j) {
        int rr = r0 - 3 + j;
        rr = rr < 0 ? 0 : (rr >= n_rows ? n_rows - 1 : rr);
        v[j] = *(const float4*)(x + (size_t)rr * DCH + c0);
    }

    // Fused 7-tap kernel: dt=-3..3 -> W[0..6]; +1.0 at dt=0 for the residual.
    float W[7][4], bias[4];
    #pragma unroll
    for (int q = 0; q < 4; ++q) {
        const int d = c0 + q;
        const float a0 = w7[d*7+0], a1 = w7[d*7+1], a2 = w7[d*7+2], a3 = w7[d*7+3],
                    a4 = w7[d*7+4], a5 = w7[d*7+5], a6 = w7[d*7+6];
        const float f0 = w5[d*5+0], f1 = w5[d*5+1], f2 = w5[d*5+2], f3 = w5[d*5+3], f4 = w5[d*5+4];
        const float e0 = w3[d*3+0], e1 = w3[d*3+1], e2 = w3[d*3+2];
        W[0][q] = a0;
        W[1][q] = a1 + f0;
        W[2][q] = a2 + f1 + e0;
        W[3][q] = a3 + f2 + e1 + 1.0f;
        W[4][q] = a4 + f3 + e2;
        W[5][q] = a5 + f4;
        W[6][q] = a6;
        bias[q] = b3[d] + b5[d] + b7[d];
    }

    // Bag for r0 (wave-uniform).
    int b = 0;
    while (b + 1 < n_bags && soff[b + 1] <= r0) ++b;

    // ---- row r0: window v[0..6] ----
    {
        const int t   = r0 - soff[b] - 1;            // -1 => cls row
        const int Lb1 = soff[b + 1] - soff[b] - 1;   // body length
        float4 o;
        if (t < 0) {
            o = v[3];
        } else {
            float a0 = bias[0], a1 = bias[1], a2 = bias[2], a3 = bias[3];
            #pragma unroll
            for (int j = 0; j < 7; ++j) {
                const int tp = t + j - 3;
                const float m = (tp >= 0 && tp < Lb1) ? 1.0f : 0.0f;
                a0 += (m * W[j][0]) * v[j].x;
                a1 += (m * W[j][1]) * v[j].y;
                a2 += (m * W[j][2]) * v[j].z;
                a3 += (m * W[j][3]) * v[j].w;
            }
            o = make_float4(a0, a1, a2, a3);
        }
        *(float4*)(out + (size_t)r0 * DCH + c0) = o;
    }

    // ---- row r1: window v[1..7] ----
    if (r1 < n_rows) {
        int b1 = b;
        while (b1 + 1 < n_bags && soff[b1 + 1] <= r1) ++b1;
        const int t   = r1 - soff[b1] - 1;
        const int Lb1 = soff[b1 + 1] - soff[b1] - 1;
        float4 o;
        if (t < 0) {
            o = v[4];
        } else {
            float a0 = bias[0], a1 = bias[1], a2 = bias[2], a3 = bias[3];
            #pragma unroll
            for (int j = 0; j < 7; ++j) {
                const int tp = t + j - 3;
                const float m = (tp >= 0 && tp < Lb1) ? 1.0f : 0.0f;
                a0 += (m * W[j][0]) * v[j + 1].x;
                a1 += (m * W[j][1]) * v[j + 1].y;
                a2 += (m * W[j][2]) * v[j + 1].z;
                a3 += (m * W[j][3]) * v[j + 1].w;
            }
            o = make_float4(a0, a1, a2, a3);
        }
        *(float4*)(out + (size_t)r1 * DCH + c0) = o;
    }
}

extern "C" void kernel_launch(void* const* d_in, const int* in_sizes, int n_in,
                              void* d_out, int out_size, void* d_ws, size_t ws_size,
                              hipStream_t stream) {
    const float* x       = (const float*)d_in[0];
    const float* w3      = (const float*)d_in[1];
    const float* b3      = (const float*)d_in[2];
    const float* w5      = (const float*)d_in[3];
    const float* b5      = (const float*)d_in[4];
    const float* w7      = (const float*)d_in[5];
    const float* b7      = (const float*)d_in[6];
    const int*   lengths = (const int*)d_in[7];

    const int n_bags = in_sizes[7];
    const int n_rows = in_sizes[0] / DCH;
    float* out = (float*)d_out;

    const int nblocks = (n_rows + 1) / 2;
    ppeg_dwconv_kernel<<<nblocks, 128, 0, stream>>>(
        x, w3, b3, w5, b5, w7, b7, lengths, out, n_rows, n_bags);
}

// Round 5
// 249.236 us; speedup vs baseline: 1.2408x; 1.2408x over previous
//
#include <hip/hip_runtime.h>

#define DCH   512   // channels
#define RPB   32    // rows per block (strip length); 63488 = 1984 * 32
#define CHUNK 4     // rows computed per pipeline stage

typedef float fx4 __attribute__((ext_vector_type(4)));

__global__ __launch_bounds__(128, 4) void ppeg_dwconv_kernel(
    const float* __restrict__ x,
    const float* __restrict__ w3, const float* __restrict__ b3,
    const float* __restrict__ w5, const float* __restrict__ b5,
    const float* __restrict__ w7, const float* __restrict__ b7,
    const int* __restrict__ lengths,
    float* __restrict__ out, int n_rows, int n_bags)
{
    __shared__ int soff[32];   // prefix offsets, n_bags+1 entries
    if (threadIdx.x == 0) {
        int acc = 0;
        for (int i = 0; i < n_bags; ++i) { soff[i] = acc; acc += lengths[i]; }
        soff[n_bags] = acc;
    }
    __syncthreads();

    const int tid = threadIdx.x;
    const int c0  = tid * 4;            // this thread's 4 channels

    const int s0 = blockIdx.x * RPB;
    if (s0 >= n_rows) return;
    const int s1 = (s0 + RPB < n_rows) ? s0 + RPB : n_rows;

    // Fused 7-tap kernel: dt=-3..3 -> W[0..6]; +1.0 at dt=0 for the residual.
    float W[7][4], bias[4];
    #pragma unroll
    for (int q = 0; q < 4; ++q) {
        const int d = c0 + q;
        const float a0 = w7[d*7+0], a1 = w7[d*7+1], a2 = w7[d*7+2], a3 = w7[d*7+3],
                    a4 = w7[d*7+4], a5 = w7[d*7+5], a6 = w7[d*7+6];
        const float f0 = w5[d*5+0], f1 = w5[d*5+1], f2 = w5[d*5+2], f3 = w5[d*5+3], f4 = w5[d*5+4];
        const float e0 = w3[d*3+0], e1 = w3[d*3+1], e2 = w3[d*3+2];
        W[0][q] = a0;
        W[1][q] = a1 + f0;
        W[2][q] = a2 + f1 + e0;
        W[3][q] = a3 + f2 + e1 + 1.0f;
        W[4][q] = a4 + f3 + e2;
        W[5][q] = a5 + f4;
        W[6][q] = a6;
        bias[q] = b3[d] + b5[d] + b7[d];
    }

    // Row load with clamped address; out-of-bag taps are masked, out-of-range
    // rows are clamped (their values never contribute).
    auto ldrow = [&](int rr) -> fx4 {
        rr = rr < 0 ? 0 : (rr >= n_rows ? n_rows - 1 : rr);
        return *(const fx4*)(x + (size_t)rr * DCH + c0);
    };

    // Register ring: R[j] = row (rc - 3 + j) for the current chunk base rc.
    fx4 R[10];
    #pragma unroll
    for (int j = 0; j < 10; ++j) R[j] = ldrow(s0 - 3 + j);

    // Bag index for s0 (wave-uniform).
    int b = 0;
    while (b + 1 < n_bags && soff[b + 1] <= s0) ++b;

    for (int rc = s0; rc < s1; rc += CHUNK) {
        // Prefetch next chunk's 4 rows (rc+7 .. rc+10) — issued before compute.
        fx4 P[CHUNK];
        #pragma unroll
        for (int j = 0; j < CHUNK; ++j) P[j] = ldrow(rc + 7 + j);

        #pragma unroll
        for (int i = 0; i < CHUNK; ++i) {
            const int r = rc + i;
            if (r >= s1) break;
            while (b + 1 < n_bags && soff[b + 1] <= r) ++b;
            const int t   = r - soff[b] - 1;            // -1 => cls row
            const int Lb1 = soff[b + 1] - soff[b] - 1;  // body length

            fx4 o;
            if (t < 0) {
                o = R[i + 3];                            // cls pass-through
            } else {
                float a0 = bias[0], a1 = bias[1], a2 = bias[2], a3 = bias[3];
                #pragma unroll
                for (int j = 0; j < 7; ++j) {
                    const int tp = t + j - 3;
                    const float m = (tp >= 0 && tp < Lb1) ? 1.0f : 0.0f;
                    const fx4 v = R[i + j];
                    a0 += (m * W[j][0]) * v.x;
                    a1 += (m * W[j][1]) * v.y;
                    a2 += (m * W[j][2]) * v.z;
                    a3 += (m * W[j][3]) * v.w;
                }
                o = (fx4){a0, a1, a2, a3};
            }
            __builtin_nontemporal_store(o, (fx4*)(out + (size_t)r * DCH + c0));
        }

        // Shift ring down by CHUNK; append prefetched rows.
        #pragma unroll
        for (int j = 0; j < 10 - CHUNK; ++j) R[j] = R[j + CHUNK];
        #pragma unroll
        for (int j = 0; j < CHUNK; ++j) R[10 - CHUNK + j] = P[j];
    }
}

extern "C" void kernel_launch(void* const* d_in, const int* in_sizes, int n_in,
                              void* d_out, int out_size, void* d_ws, size_t ws_size,
                              hipStream_t stream) {
    const float* x       = (const float*)d_in[0];
    const float* w3      = (const float*)d_in[1];
    const float* b3      = (const float*)d_in[2];
    const float* w5      = (const float*)d_in[3];
    const float* b5      = (const float*)d_in[4];
    const float* w7      = (const float*)d_in[5];
    const float* b7      = (const float*)d_in[6];
    const int*   lengths = (const int*)d_in[7];

    const int n_bags = in_sizes[7];
    const int n_rows = in_sizes[0] / DCH;
    float* out = (float*)d_out;

    const int nblocks = (n_rows + RPB - 1) / RPB;
    ppeg_dwconv_kernel<<<nblocks, 128, 0, stream>>>(
        x, w3, b3, w5, b5, w7, b7, lengths, out, n_rows, n_bags);
}